// Round 9
// baseline (281.604 us; speedup 1.0000x reference)
//
#include <hip/hip_runtime.h>
#include <math.h>

typedef __attribute__((ext_vector_type(8))) short short8;
typedef __attribute__((ext_vector_type(4))) float floatx4;

__device__ __forceinline__ float bf2f(unsigned short u) {
    union { unsigned int u; float f; } v;
    v.u = ((unsigned int)u) << 16;
    return v.f;
}

__device__ __forceinline__ unsigned short f2bf(float f) {
    union { float f; unsigned int u; } v;
    v.f = f;
    unsigned int r = v.u + 0x7fffu + ((v.u >> 16) & 1u);  // RNE
    return (unsigned short)(r >> 16);
}

__device__ __forceinline__ void gload16_lds(const void* g, void* l) {
    __builtin_amdgcn_global_load_lds(
        (const __attribute__((address_space(1))) unsigned int*)g,
        (__attribute__((address_space(3))) unsigned int*)l, 16, 0, 0);
}

__device__ __forceinline__ ushort4 cvt4(float4 v, float fa) {
    ushort4 o;
    o.x = f2bf(v.x * fa); o.y = f2bf(v.y * fa);
    o.z = f2bf(v.z * fa); o.w = f2bf(v.w * fa);
    return o;
}

// ---------------- fused prep: rows (wave-per-row) | transpose(value) ----------
__global__ __launch_bounds__(256) void prep_kernel(
    const float* __restrict__ x, const float* __restrict__ key,
    const float* __restrict__ temp, const float* __restrict__ val,
    unsigned short* __restrict__ xb, unsigned short* __restrict__ kf,
    unsigned short* __restrict__ VT, float* __restrict__ rowsq,
    int* __restrict__ cnt,
    int M, int T, int D, int Dout, int nRowBlocks) {
    const int bid = blockIdx.x;
    if (bid == 0 && threadIdx.x < 64) cnt[threadIdx.x] = 0;  // stripe counters
    if (bid < nRowBlocks) {
        const int lane = threadIdx.x & 63;
        const int nWaves = nRowBlocks << 2;  // 4 waves per block
        const int totRows = M + T;
        for (int row = (bid << 2) | (int)(threadIdx.x >> 6); row < totRows;
             row += nWaves) {
            const bool isx = row < M;
            const int r = isx ? row : row - M;
            const float4* s4 =
                (const float4*)(isx ? (x + (size_t)r * D) : (key + (size_t)r * D));
            float4 v0 = s4[lane];
            float4 v1 = s4[lane + 64];
            float4 v2 = s4[lane + 128];
            float4 v3 = s4[lane + 192];
            float s = v0.x * v0.x + v0.y * v0.y + v0.z * v0.z + v0.w * v0.w;
            s += v1.x * v1.x + v1.y * v1.y + v1.z * v1.z + v1.w * v1.w;
            s += v2.x * v2.x + v2.y * v2.y + v2.z * v2.z + v2.w * v2.w;
            s += v3.x * v3.x + v3.y * v3.y + v3.z * v3.z + v3.w * v3.w;
#pragma unroll
            for (int o = 32; o > 0; o >>= 1) s += __shfl_xor(s, o, 64);
            float fa = 1.0f / fmaxf(sqrtf(s), 1e-12f);
            if (isx) {
                if (lane == 0) rowsq[r] = 0.0f;
            } else {
                fa = fa / (1.0f + expf(-temp[r]));
            }
            ushort4* dst =
                (ushort4*)(isx ? (xb + (size_t)r * D) : (kf + (size_t)r * D));
            dst[lane] = cvt4(v0, fa);
            dst[lane + 64] = cvt4(v1, fa);
            dst[lane + 128] = cvt4(v2, fa);
            dst[lane + 192] = cvt4(v3, fa);
        }
    } else {
        __shared__ unsigned short tile[64][65];
        const int idx = bid - nRowBlocks;
        const int nCt = Dout >> 6;
        const int c0 = (idx % nCt) * 64;
        const int r0 = (idx / nCt) * 64;
        const int t = threadIdx.x;
        for (int i = t; i < 4096; i += 256) {
            int rr = i >> 6, cc = i & 63;
            tile[rr][cc] = f2bf(val[(size_t)(r0 + rr) * Dout + c0 + cc]);
        }
        __syncthreads();
        for (int i = t; i < 4096; i += 256) {
            int rr = i >> 6, cc = i & 63;
            VT[(size_t)(c0 + rr) * T + r0 + cc] = tile[cc][rr];
        }
    }
}

// ===== 256x128 bf16 MFMA GEMM, counted-vmcnt pipeline, 2 blocks/CU ===========
// R5/R7 verified structure: 4 waves 2Mx2N, per-wave 128x64, BK=32, 3-slot LDS
// ring 72KB, st_16x32 swizzle both-sides, vmcnt(6) steady, lgkm staircase,
// K-loop unrolled x6 (immediate LDS addressing).
// R9 change — gelu fused into MODE 0 epilogue (gelu kernel deleted):
//   sim values are touched only by the block that computes them (in acc);
//   the cross-block dependency is ONLY rowsq. Each block: (1) atomicAdd its
//   rowsq contributions, (2) syncthreads (drains vmcnt -> atomics complete),
//   (3) tid0: threadfence + cnt[bx]++ + spin until all N/128 col-blocks of
//   the stripe arrived, (4) threadfence (L1 inv), read final rowsq, gelu the
//   in-register acc, store sim ONCE (post-gelu). Grid = 512 blocks = exactly
//   2/CU (LDS-limited) -> all co-resident -> spin is deadlock-free.
// MODE 0: C(bf16) = gelu(acc * sqrtN/sqrt(rowsq))   (GEMM1+gelu: sim)
// MODE 1: C(fp32) = acc                             (GEMM2: out)
template <int MODE>
__global__ __launch_bounds__(256, 2) void gemm_pipe(
    const unsigned short* __restrict__ A, const unsigned short* __restrict__ B,
    void* __restrict__ Cv, float* __restrict__ rowsq, int* __restrict__ cnt,
    int M, int N, int K) {
    __shared__ __align__(16) char smem[73728];  // 3 slots x (A 16KB | B 8KB)
    const int tid = threadIdx.x;
    const int lane = tid & 63;
    const int w = tid >> 6;       // wave 0..3
    const int wr = w >> 1;        // 0..1  (M)
    const int wc = w & 1;         // 0..1  (N)
    const int m0 = blockIdx.x * 256;
    const int n0 = blockIdx.y * 128;
    const int q = lane >> 4;
    const int cl = lane & 15;

    // staging addressing (pre-swizzled global source, rule #21)
    const int srow = lane >> 2;
    const int sch = (lane & 3) ^ ((lane & 32) >> 4);
    const unsigned short* gA = A + (size_t)(m0 + w * 16 + srow) * K + sch * 8;
    const unsigned short* gB = B + (size_t)(n0 + w * 16 + srow) * K + sch * 8;
    const unsigned short* rA0 = gA;
    const unsigned short* rA1 = gA + (size_t)64 * K;
    const unsigned short* rA2 = gA + (size_t)128 * K;
    const unsigned short* rA3 = gA + (size_t)192 * K;
    const unsigned short* rB0 = gB;
    const unsigned short* rB1 = gB + (size_t)64 * K;

    // LDS staging dest bases (wave-uniform; HW appends lane*16)
    char* stA = smem + w * 1024;
    char* stB = stA + 16384;

    // ds_read per-lane bases (swizzled)
    const int LB = ((cl * 64 + q * 16) ^ ((lane & 8) << 2));
    const char* rdA = (const char*)smem + LB + wr * 8192;
    const char* rdB = (const char*)smem + LB + 16384 + wc * 4096;

    floatx4 acc[8][4];
#pragma unroll
    for (int i = 0; i < 8; i++)
#pragma unroll
        for (int j = 0; j < 4; j++) acc[i][j] = (floatx4){0.f, 0.f, 0.f, 0.f};

    short8 af0[4], af1[4], bf0[4], bf1[4];

    // prologue: stage tiles 0 (slot 0) and 1 (slot 1); wait tile 0 (6 fly)
    gload16_lds(rA0, stA);
    gload16_lds(rA1, stA + 4096);
    gload16_lds(rB0, stB);
    gload16_lds(rA2, stA + 8192);
    gload16_lds(rA3, stA + 12288);
    gload16_lds(rB1, stB + 4096);
    gload16_lds(rA0 + 32, stA + 24576);
    gload16_lds(rA1 + 32, stA + 24576 + 4096);
    gload16_lds(rB0 + 32, stB + 24576);
    gload16_lds(rA2 + 32, stA + 24576 + 8192);
    gload16_lds(rA3 + 32, stA + 24576 + 12288);
    gload16_lds(rB1 + 32, stB + 24576 + 4096);
    asm volatile("s_waitcnt vmcnt(6)" ::: "memory");
    __builtin_amdgcn_s_barrier();
    // group pointers pre-offset to tile 2 (staged during tile 0)
    rA0 += 64; rA1 += 64; rA2 += 64; rA3 += 64; rB0 += 64; rB1 += 64;

#define MFMA4(AFR, BF, RO)                                                   \
    _Pragma("unroll") for (int nt = 0; nt < 4; ++nt)                         \
        acc[RO][nt] = __builtin_amdgcn_mfma_f32_16x16x32_bf16(               \
            AFR, BF[nt], acc[RO][nt], 0, 0, 0);

#define STEP3(AFR, BF, RO)                                                   \
    asm volatile("s_waitcnt lgkmcnt(3)" ::: "memory");                       \
    __builtin_amdgcn_sched_barrier(0);                                       \
    MFMA4(AFR, BF, RO)
#define STEP2(AFR, BF, RO)                                                   \
    asm volatile("s_waitcnt lgkmcnt(2)" ::: "memory");                       \
    __builtin_amdgcn_sched_barrier(0);                                       \
    MFMA4(AFR, BF, RO)
#define STEP1(AFR, BF, RO)                                                   \
    asm volatile("s_waitcnt lgkmcnt(1)" ::: "memory");                       \
    __builtin_amdgcn_sched_barrier(0);                                       \
    MFMA4(AFR, BF, RO)
#define STEP0(AFR, BF, RO)                                                   \
    asm volatile("s_waitcnt lgkmcnt(0)" ::: "memory");                       \
    __builtin_amdgcn_sched_barrier(0);                                       \
    MFMA4(AFR, BF, RO)

// pinned-order ds_read: bf group, then af one by one (fences fix lgkm mapping)
#define READS_P0(SLOT, BF)                                                   \
    BF[0] = *(const short8*)(rdB + SLOT * 24576);                            \
    BF[1] = *(const short8*)(rdB + SLOT * 24576 + 1024);                     \
    BF[2] = *(const short8*)(rdB + SLOT * 24576 + 2048);                     \
    BF[3] = *(const short8*)(rdB + SLOT * 24576 + 3072);                     \
    __builtin_amdgcn_sched_barrier(0);                                       \
    af0[0] = *(const short8*)(rdA + SLOT * 24576);                           \
    __builtin_amdgcn_sched_barrier(0);                                       \
    af0[1] = *(const short8*)(rdA + SLOT * 24576 + 1024);                    \
    __builtin_amdgcn_sched_barrier(0);                                       \
    af0[2] = *(const short8*)(rdA + SLOT * 24576 + 2048);                    \
    __builtin_amdgcn_sched_barrier(0);                                       \
    af0[3] = *(const short8*)(rdA + SLOT * 24576 + 3072);                    \
    __builtin_amdgcn_sched_barrier(0);

#define READS_P1(SLOT)                                                       \
    af1[0] = *(const short8*)(rdA + SLOT * 24576 + 4096);                    \
    __builtin_amdgcn_sched_barrier(0);                                       \
    af1[1] = *(const short8*)(rdA + SLOT * 24576 + 5120);                    \
    __builtin_amdgcn_sched_barrier(0);                                       \
    af1[2] = *(const short8*)(rdA + SLOT * 24576 + 6144);                    \
    __builtin_amdgcn_sched_barrier(0);                                       \
    af1[3] = *(const short8*)(rdA + SLOT * 24576 + 7168);                    \
    __builtin_amdgcn_sched_barrier(0);

#define TILE(SLOT, SSLOT, BF, KOFF)                                          \
    {                                                                        \
        READS_P0(SLOT, BF)                                                   \
        gload16_lds(rA0 + KOFF, stA + SSLOT * 24576);                        \
        gload16_lds(rA1 + KOFF, stA + SSLOT * 24576 + 4096);                 \
        gload16_lds(rB0 + KOFF, stB + SSLOT * 24576);                        \
        __builtin_amdgcn_s_barrier();                                        \
        __builtin_amdgcn_s_setprio(1);                                       \
        STEP3(af0[0], BF, 0)                                                 \
        STEP2(af0[1], BF, 1)                                                 \
        STEP1(af0[2], BF, 2)                                                 \
        STEP0(af0[3], BF, 3)                                                 \
        __builtin_amdgcn_s_setprio(0);                                       \
        __builtin_amdgcn_s_barrier();                                        \
        READS_P1(SLOT)                                                       \
        gload16_lds(rA2 + KOFF, stA + SSLOT * 24576 + 8192);                 \
        gload16_lds(rA3 + KOFF, stA + SSLOT * 24576 + 12288);                \
        gload16_lds(rB1 + KOFF, stB + SSLOT * 24576 + 4096);                 \
        asm volatile("s_waitcnt vmcnt(6)" ::: "memory");                     \
        __builtin_amdgcn_s_barrier();                                        \
        __builtin_amdgcn_s_setprio(1);                                       \
        STEP3(af1[0], BF, 4)                                                 \
        STEP2(af1[1], BF, 5)                                                 \
        STEP1(af1[2], BF, 6)                                                 \
        STEP0(af1[3], BF, 7)                                                 \
        __builtin_amdgcn_s_setprio(0);                                       \
        __builtin_amdgcn_s_barrier();                                        \
    }

#define TILE_TAIL(SLOT, BF, DRAIN)                                           \
    {                                                                        \
        READS_P0(SLOT, BF)                                                   \
        __builtin_amdgcn_s_barrier();                                        \
        __builtin_amdgcn_s_setprio(1);                                       \
        STEP3(af0[0], BF, 0)                                                 \
        STEP2(af0[1], BF, 1)                                                 \
        STEP1(af0[2], BF, 2)                                                 \
        STEP0(af0[3], BF, 3)                                                 \
        __builtin_amdgcn_s_setprio(0);                                       \
        __builtin_amdgcn_s_barrier();                                        \
        READS_P1(SLOT)                                                       \
        if (DRAIN) asm volatile("s_waitcnt vmcnt(0)" ::: "memory");          \
        __builtin_amdgcn_s_barrier();                                        \
        __builtin_amdgcn_s_setprio(1);                                       \
        STEP3(af1[0], BF, 4)                                                 \
        STEP2(af1[1], BF, 5)                                                 \
        STEP1(af1[2], BF, 6)                                                 \
        STEP0(af1[3], BF, 7)                                                 \
        __builtin_amdgcn_s_setprio(0);                                       \
        __builtin_amdgcn_s_barrier();                                        \
    }

    for (int g = 0; g < 5; ++g) {
        TILE(0, 2, bf0, 0)
        TILE(1, 0, bf1, 32)
        TILE(2, 1, bf0, 64)
        TILE(0, 2, bf1, 96)
        TILE(1, 0, bf0, 128)
        TILE(2, 1, bf1, 160)
        rA0 += 192; rA1 += 192; rA2 += 192; rA3 += 192;
        rB0 += 192; rB1 += 192;
    }
    TILE_TAIL(0, bf0, 1)
    TILE_TAIL(1, bf1, 0)

#undef TILE
#undef TILE_TAIL
#undef READS_P0
#undef READS_P1
#undef STEP3
#undef STEP2
#undef STEP1
#undef STEP0
#undef MFMA4

    // epilogue — C/D layout: col = lane&15, row = q*4 + reg
    if (MODE == 0) {
        // pass 1: rowsq contributions only
#pragma unroll
        for (int mt = 0; mt < 8; ++mt) {
#pragma unroll
            for (int r = 0; r < 4; ++r) {
                float ssq = 0.f;
#pragma unroll
                for (int nt = 0; nt < 4; ++nt) {
                    float v = acc[mt][nt][r];
                    ssq += v * v;
                }
#pragma unroll
                for (int o = 1; o < 16; o <<= 1) ssq += __shfl_xor(ssq, o, 64);
                if (cl == 0)
                    atomicAdd(&rowsq[m0 + wr * 128 + mt * 16 + q * 4 + r], ssq);
            }
        }
        // stripe rendezvous: all N/128 col-blocks of this m-stripe
        __syncthreads();  // drains vmcnt -> all waves' atomics complete
        const int NB = (int)gridDim.y;
        if (tid == 0) {
            __threadfence();
            atomicAdd(&cnt[blockIdx.x], 1);
            while (atomicAdd(&cnt[blockIdx.x], 0) < NB)
                __builtin_amdgcn_s_sleep(16);
        }
        __syncthreads();
        __threadfence();  // invalidate L1 before reading final rowsq
        const float sqrtN = sqrtf((float)N);
        const float kk = 0.70710678118654752f;
        unsigned short* C = (unsigned short*)Cv;
#pragma unroll
        for (int mt = 0; mt < 8; ++mt) {
#pragma unroll
            for (int r = 0; r < 4; ++r) {
                const int m = m0 + wr * 128 + mt * 16 + q * 4 + r;
                const float scale = sqrtN / fmaxf(sqrtf(rowsq[m]), 1e-30f);
#pragma unroll
                for (int nt = 0; nt < 4; ++nt) {
                    float z = acc[mt][nt][r] * scale;
                    float gz = 0.5f * z * (1.0f + erff(z * kk));
                    C[(size_t)m * N + n0 + wc * 64 + nt * 16 + cl] = f2bf(gz);
                }
            }
        }
    } else {
        float* C = (float*)Cv;
#pragma unroll
        for (int mt = 0; mt < 8; ++mt) {
#pragma unroll
            for (int r = 0; r < 4; ++r) {
                const int m = m0 + wr * 128 + mt * 16 + q * 4 + r;
#pragma unroll
                for (int nt = 0; nt < 4; ++nt)
                    C[(size_t)m * N + n0 + wc * 64 + nt * 16 + cl] =
                        acc[mt][nt][r];
            }
        }
    }
}

extern "C" void kernel_launch(void* const* d_in, const int* in_sizes, int n_in,
                              void* d_out, int out_size, void* d_ws, size_t ws_size,
                              hipStream_t stream) {
    const float* x    = (const float*)d_in[0];  // [M, D] fp32
    const float* key  = (const float*)d_in[1];  // [T, D] fp32
    const float* val  = (const float*)d_in[2];  // [T, Dout] fp32
    const float* temp = (const float*)d_in[3];  // [T] fp32
    float* out = (float*)d_out;                 // [M, Dout] fp32

    const int T = in_sizes[3];              // 1024
    const int D = in_sizes[1] / T;          // 1024
    const int Dout = in_sizes[2] / T;       // 1024
    const int M = in_sizes[0] / D;          // 16384

    char* ws = (char*)d_ws;
    size_t off = 0;
    unsigned short* xb  = (unsigned short*)(ws + off); off += (size_t)M * D * 2;
    unsigned short* sim = (unsigned short*)(ws + off); off += (size_t)M * T * 2;
    unsigned short* kf  = (unsigned short*)(ws + off); off += (size_t)T * D * 2;
    unsigned short* VT  = (unsigned short*)(ws + off); off += (size_t)Dout * T * 2;
    float* rowsq = (float*)(ws + off); off += (size_t)M * 4;
    int* cnt = (int*)(ws + off); off += 256 * 4;
    (void)ws_size; (void)n_in; (void)out_size;

    const int nTrTiles = (T >> 6) * (Dout >> 6);
    const int nRowBlocks = 1024;  // 4096 waves grid-striding M+T rows
    prep_kernel<<<nRowBlocks + nTrTiles, 256, 0, stream>>>(
        x, key, temp, val, xb, kf, VT, rowsq, cnt, M, T, D, Dout, nRowBlocks);
    gemm_pipe<0><<<dim3(M / 256, T / 128), 256, 0, stream>>>(xb, kf, sim, rowsq,
                                                             cnt, M, T, D);
    gemm_pipe<1><<<dim3(M / 256, Dout / 128), 256, 0, stream>>>(
        sim, VT, out, nullptr, nullptr, M, Dout, T);
}

// Round 10
// 208.241 us; speedup vs baseline: 1.3523x; 1.3523x over previous
//
#include <hip/hip_runtime.h>
#include <math.h>

typedef __attribute__((ext_vector_type(8))) short short8;
typedef __attribute__((ext_vector_type(4))) float floatx4;

__device__ __forceinline__ float bf2f(unsigned short u) {
    union { unsigned int u; float f; } v;
    v.u = ((unsigned int)u) << 16;
    return v.f;
}

__device__ __forceinline__ unsigned short f2bf(float f) {
    union { float f; unsigned int u; } v;
    v.f = f;
    unsigned int r = v.u + 0x7fffu + ((v.u >> 16) & 1u);  // RNE
    return (unsigned short)(r >> 16);
}

__device__ __forceinline__ void gload16_lds(const void* g, void* l) {
    __builtin_amdgcn_global_load_lds(
        (const __attribute__((address_space(1))) unsigned int*)g,
        (__attribute__((address_space(3))) unsigned int*)l, 16, 0, 0);
}

__device__ __forceinline__ ushort4 cvt4(float4 v, float fa) {
    ushort4 o;
    o.x = f2bf(v.x * fa); o.y = f2bf(v.y * fa);
    o.z = f2bf(v.z * fa); o.w = f2bf(v.w * fa);
    return o;
}

// ---------------- fused prep: rows (wave-per-row) | transpose(value) ----------
__global__ __launch_bounds__(256) void prep_kernel(
    const float* __restrict__ x, const float* __restrict__ key,
    const float* __restrict__ temp, const float* __restrict__ val,
    unsigned short* __restrict__ xb, unsigned short* __restrict__ kf,
    unsigned short* __restrict__ VT, float* __restrict__ rowsq,
    int M, int T, int D, int Dout, int nRowBlocks) {
    const int bid = blockIdx.x;
    if (bid < nRowBlocks) {
        const int lane = threadIdx.x & 63;
        const int nWaves = nRowBlocks << 2;  // 4 waves per block
        const int totRows = M + T;
        for (int row = (bid << 2) | (int)(threadIdx.x >> 6); row < totRows;
             row += nWaves) {
            const bool isx = row < M;
            const int r = isx ? row : row - M;
            const float4* s4 =
                (const float4*)(isx ? (x + (size_t)r * D) : (key + (size_t)r * D));
            float4 v0 = s4[lane];
            float4 v1 = s4[lane + 64];
            float4 v2 = s4[lane + 128];
            float4 v3 = s4[lane + 192];
            float s = v0.x * v0.x + v0.y * v0.y + v0.z * v0.z + v0.w * v0.w;
            s += v1.x * v1.x + v1.y * v1.y + v1.z * v1.z + v1.w * v1.w;
            s += v2.x * v2.x + v2.y * v2.y + v2.z * v2.z + v2.w * v2.w;
            s += v3.x * v3.x + v3.y * v3.y + v3.z * v3.z + v3.w * v3.w;
#pragma unroll
            for (int o = 32; o > 0; o >>= 1) s += __shfl_xor(s, o, 64);
            float fa = 1.0f / fmaxf(sqrtf(s), 1e-12f);
            if (isx) {
                if (lane == 0) rowsq[r] = 0.0f;
            } else {
                fa = fa / (1.0f + expf(-temp[r]));
            }
            ushort4* dst =
                (ushort4*)(isx ? (xb + (size_t)r * D) : (kf + (size_t)r * D));
            dst[lane] = cvt4(v0, fa);
            dst[lane + 64] = cvt4(v1, fa);
            dst[lane + 128] = cvt4(v2, fa);
            dst[lane + 192] = cvt4(v3, fa);
        }
    } else {
        __shared__ unsigned short tile[64][65];
        const int idx = bid - nRowBlocks;
        const int nCt = Dout >> 6;
        const int c0 = (idx % nCt) * 64;
        const int r0 = (idx / nCt) * 64;
        const int t = threadIdx.x;
        for (int i = t; i < 4096; i += 256) {
            int rr = i >> 6, cc = i & 63;
            tile[rr][cc] = f2bf(val[(size_t)(r0 + rr) * Dout + c0 + cc]);
        }
        __syncthreads();
        for (int i = t; i < 4096; i += 256) {
            int rr = i >> 6, cc = i & 63;
            VT[(size_t)(c0 + rr) * T + r0 + cc] = tile[cc][rr];
        }
    }
}

// ===== 256x256 bf16 MFMA GEMM — m201-style 4-phase quadrant pipeline ========
// C[M,N] = A[M,K] * B[N,K]^T. 8 waves (2M x 4N), per-wave 128x64. BK=64.
// LDS 128KB dynamic: 2 slots x (A 32KB | B 32KB); layout per operand:
//   [ksub(2) x 16KB][rowsub(16) x 1KB][16x32 subtile, st_16x32 swizzled].
// Per K-tile, 4 phases (quadrants of the wave's 128x64 output, K=64 each):
//   ph1: 12 ds_reads (A0:8, B1:4) | stage Ah0(t+1)->other slot | MFMA Q01
//   ph2:  4 ds_reads (B0)         | stage Ah1(t+1)->other slot | MFMA Q00
//   ph3:  8 ds_reads (A1)         | stage Bh0(t+2)->own slot   | MFMA Q10
//   ph4:  0 reads                 | stage Bh1(t+2)->own slot   | MFMA Q11
//         + vmcnt(4) (lands Ah(t+1); Bh(t+2) stays in flight) + barrier
// One barrier per phase. Free/stage ledger: A-halves free at end-ph3 (staged
// next tile ph1/2 into other slot); B-halves free at end-ph2 (staged ph3/4
// into own slot, after the end-ph2 barrier). Min stage->read lead: 3 phases.
// MODE 0: C(bf16) = acc; rowsq[m] += sum(acc^2)   (GEMM1: sim)
// MODE 1: C(fp32) = acc                           (GEMM2: out)
template <int MODE>
__global__ __launch_bounds__(512, 2) void gemm8p(
    const unsigned short* __restrict__ A, const unsigned short* __restrict__ B,
    void* __restrict__ Cv, float* __restrict__ rowsq, int M, int N, int K) {
    extern __shared__ __align__(16) char smem[];  // 131072
    const int tid = threadIdx.x;
    const int lane = tid & 63;
    const int w = tid >> 6;   // 0..7
    const int wr = w >> 2;    // 0..1 (M)
    const int wc = w & 3;     // 0..3 (N)
    const int m0 = blockIdx.x * 256;
    const int n0 = blockIdx.y * 256;
    const int q = lane >> 4;
    const int cl = lane & 15;

    // staging source (pre-swizzled, rule #21): lane -> subtile row lane>>2,
    // 16B chunk (lane&3)^(rowbit3)
    const int srow = lane >> 2;
    const int sch = (lane & 3) ^ ((lane & 32) >> 4);
    const unsigned short* rA0 = A + (size_t)(m0 + w * 16 + srow) * K + sch * 8;
    const unsigned short* rA1 = rA0 + (size_t)128 * K;
    const unsigned short* rB0 = B + (size_t)(n0 + w * 16 + srow) * K + sch * 8;
    const unsigned short* rB1 = rB0 + (size_t)128 * K;

    // LDS staging base (wave-uniform; HW appends lane*16). Dest for a call
    // (slotB, opB, ksub, h): st + slotB + opB*32768 + ksub*16384 + h*8192
    char* st = smem + w * 1024;

    // ds_read per-lane bases (swizzled): rd + ksub*16384 + rowsub*1024 (A)
    //                                    rd + 32768 + ksub*16384 + ... (B)
    const int LB = ((cl * 64 + q * 16) ^ ((lane & 8) << 2));
    const char* rd0 = (const char*)smem + LB;
    const char* rd1 = rd0 + 65536;

    floatx4 acc[8][4];
#pragma unroll
    for (int i = 0; i < 8; i++)
#pragma unroll
        for (int j = 0; j < 4; j++) acc[i][j] = (floatx4){0.f, 0.f, 0.f, 0.f};

    short8 a0[2][4], a1[2][4], b0[2][2], b1[2][2];

#define RD_A(DST, RD, MSB)                                                   \
    _Pragma("unroll") for (int ks = 0; ks < 2; ++ks)                         \
        _Pragma("unroll") for (int mm = 0; mm < 4; ++mm)                     \
            DST[ks][mm] = *(const short8*)(RD + ks * 16384 +                 \
                                           (wr * 8 + MSB + mm) * 1024);

#define RD_B(DST, RD, NSB)                                                   \
    _Pragma("unroll") for (int ks = 0; ks < 2; ++ks)                         \
        _Pragma("unroll") for (int nn = 0; nn < 2; ++nn)                     \
            DST[ks][nn] = *(const short8*)(RD + 32768 + ks * 16384 +         \
                                           (wc * 4 + NSB + nn) * 1024);

#define MQ(MB, NB, AF, BFu)                                                  \
    _Pragma("unroll") for (int ks = 0; ks < 2; ++ks)                         \
        _Pragma("unroll") for (int mm = 0; mm < 4; ++mm)                     \
            _Pragma("unroll") for (int nn = 0; nn < 2; ++nn)                 \
                acc[MB + mm][NB + nn] =                                      \
                    __builtin_amdgcn_mfma_f32_16x16x32_bf16(                 \
                        AF[ks][mm], BFu[ks][nn], acc[MB + mm][NB + nn],      \
                        0, 0, 0);

#define LGKM0                                                                \
    asm volatile("s_waitcnt lgkmcnt(0)" ::: "memory");                       \
    __builtin_amdgcn_sched_barrier(0);

#define VM4 asm volatile("s_waitcnt vmcnt(4)" ::: "memory");
#define VM0 asm volatile("s_waitcnt vmcnt(0)" ::: "memory");

// One BK=64 tile. RD: own-slot read base; SBO: other-slot byte; SBS: own-slot
// byte; AEN/BEN: stage enables (Ah(t+1)/Bh(t+2)); AOFF/BOFF: k elem offsets.
#define TILE(RD, SBO, SBS, AEN, BEN, AOFF, BOFF, VMCODE)                     \
    {                                                                        \
        RD_A(a0, RD, 0)                                                      \
        RD_B(b1, RD, 2)                                                      \
        if (AEN) {                                                           \
            gload16_lds(rA0 + (AOFF), st + (SBO));                           \
            gload16_lds(rA0 + (AOFF) + 32, st + (SBO) + 16384);              \
        }                                                                    \
        LGKM0                                                                \
        __builtin_amdgcn_s_setprio(1);                                       \
        MQ(0, 2, a0, b1)                                                     \
        __builtin_amdgcn_s_setprio(0);                                       \
        __builtin_amdgcn_s_barrier();                                        \
        RD_B(b0, RD, 0)                                                      \
        if (AEN) {                                                           \
            gload16_lds(rA1 + (AOFF), st + (SBO) + 8192);                    \
            gload16_lds(rA1 + (AOFF) + 32, st + (SBO) + 24576);              \
        }                                                                    \
        LGKM0                                                                \
        __builtin_amdgcn_s_setprio(1);                                       \
        MQ(0, 0, a0, b0)                                                     \
        __builtin_amdgcn_s_setprio(0);                                       \
        __builtin_amdgcn_s_barrier();                                        \
        RD_A(a1, RD, 4)                                                      \
        if (BEN) {                                                           \
            gload16_lds(rB0 + (BOFF), st + (SBS) + 32768);                   \
            gload16_lds(rB0 + (BOFF) + 32, st + (SBS) + 49152);              \
        }                                                                    \
        LGKM0                                                                \
        __builtin_amdgcn_s_setprio(1);                                       \
        MQ(4, 0, a1, b0)                                                     \
        __builtin_amdgcn_s_setprio(0);                                       \
        __builtin_amdgcn_s_barrier();                                        \
        if (BEN) {                                                           \
            gload16_lds(rB1 + (BOFF), st + (SBS) + 40960);                   \
            gload16_lds(rB1 + (BOFF) + 32, st + (SBS) + 57344);              \
        }                                                                    \
        __builtin_amdgcn_s_setprio(1);                                       \
        MQ(4, 2, a1, b1)                                                     \
        __builtin_amdgcn_s_setprio(0);                                       \
        VMCODE                                                               \
        __builtin_amdgcn_s_barrier();                                        \
    }

    // prologue (order mimics steady state):
    // Bh0(0), Bh1(0), Ah0(0), Ah1(0) -> slot0 ; Bh0(1), Bh1(1) -> slot1
    gload16_lds(rB0, st + 32768);
    gload16_lds(rB0 + 32, st + 49152);
    gload16_lds(rB1, st + 40960);
    gload16_lds(rB1 + 32, st + 57344);
    gload16_lds(rA0, st);
    gload16_lds(rA0 + 32, st + 16384);
    gload16_lds(rA1, st + 8192);
    gload16_lds(rA1 + 32, st + 24576);
    gload16_lds(rB0 + 64, st + 65536 + 32768);
    gload16_lds(rB0 + 96, st + 65536 + 49152);
    gload16_lds(rB1 + 64, st + 65536 + 40960);
    gload16_lds(rB1 + 96, st + 65536 + 57344);
    VM4
    __builtin_amdgcn_s_barrier();

    // main: NT = K/64 tiles; pairs (even slot0, odd slot1); last pair peeled
    const int NH = K >> 7;  // NT/2
    for (int g = 0; g < NH - 1; ++g) {
        TILE(rd0, 65536, 0, 1, 1, 64, 128, VM4)
        TILE(rd1, 0, 65536, 1, 1, 128, 192, VM4)
        rA0 += 128; rA1 += 128; rB0 += 128; rB1 += 128;
    }
    TILE(rd0, 65536, 0, 1, 0, 64, 0, VM0)  // tile NT-2: stage Ah(NT-1) only
    TILE(rd1, 0, 65536, 0, 0, 0, 0, )      // tile NT-1: no stage

#undef TILE
#undef RD_A
#undef RD_B
#undef MQ
#undef LGKM0
#undef VM4
#undef VM0

    // epilogue — C/D layout: col = lane&15, row = q*4 + reg
#pragma unroll
    for (int mt = 0; mt < 8; ++mt) {
#pragma unroll
        for (int r = 0; r < 4; ++r) {
            const int m = m0 + wr * 128 + mt * 16 + q * 4 + r;
            if (MODE == 0) {
                unsigned short* C = (unsigned short*)Cv;
                float ssq = 0.f;
#pragma unroll
                for (int nt = 0; nt < 4; ++nt) {
                    float v = acc[mt][nt][r];
                    ssq += v * v;
                    C[(size_t)m * N + n0 + wc * 64 + nt * 16 + cl] = f2bf(v);
                }
#pragma unroll
                for (int o = 1; o < 16; o <<= 1) ssq += __shfl_xor(ssq, o, 64);
                if (cl == 0) atomicAdd(&rowsq[m], ssq);
            } else {
                float* C = (float*)Cv;
#pragma unroll
                for (int nt = 0; nt < 4; ++nt)
                    C[(size_t)m * N + n0 + wc * 64 + nt * 16 + cl] =
                        acc[mt][nt][r];
            }
        }
    }
}

// ---------- in-place: sim = bf16(gelu_exact(sim * sqrt(T)/sqrt(rowsq[row]))) ---
__global__ __launch_bounds__(256) void gelu_kernel(unsigned short* __restrict__ sim,
                                                   const float* __restrict__ rowsq,
                                                   int nVec, int t8shift,
                                                   float sqrtT) {
    const int stride = gridDim.x * blockDim.x;
    const float kk = 0.70710678118654752f;
    for (int i = blockIdx.x * blockDim.x + threadIdx.x; i < nVec; i += stride) {
        short8 v = *(const short8*)(sim + (size_t)i * 8);
        const int row = i >> t8shift;
        const float scale = sqrtT / fmaxf(sqrtf(rowsq[row]), 1e-30f);
        short8 o;
#pragma unroll
        for (int j = 0; j < 8; j++) {
            float z = bf2f((unsigned short)v[j]) * scale;
            o[j] = (short)f2bf(0.5f * z * (1.0f + erff(z * kk)));
        }
        *(short8*)(sim + (size_t)i * 8) = o;
    }
}

extern "C" void kernel_launch(void* const* d_in, const int* in_sizes, int n_in,
                              void* d_out, int out_size, void* d_ws, size_t ws_size,
                              hipStream_t stream) {
    const float* x    = (const float*)d_in[0];  // [M, D] fp32
    const float* key  = (const float*)d_in[1];  // [T, D] fp32
    const float* val  = (const float*)d_in[2];  // [T, Dout] fp32
    const float* temp = (const float*)d_in[3];  // [T] fp32
    float* out = (float*)d_out;                 // [M, Dout] fp32

    const int T = in_sizes[3];              // 1024
    const int D = in_sizes[1] / T;          // 1024
    const int Dout = in_sizes[2] / T;       // 1024
    const int M = in_sizes[0] / D;          // 16384

    char* ws = (char*)d_ws;
    size_t off = 0;
    unsigned short* xb  = (unsigned short*)(ws + off); off += (size_t)M * D * 2;
    unsigned short* sim = (unsigned short*)(ws + off); off += (size_t)M * T * 2;
    unsigned short* kf  = (unsigned short*)(ws + off); off += (size_t)T * D * 2;
    unsigned short* VT  = (unsigned short*)(ws + off); off += (size_t)Dout * T * 2;
    float* rowsq = (float*)(ws + off); off += (size_t)M * 4;
    (void)ws_size; (void)n_in; (void)out_size;

    static bool s_attr = false;
    if (!s_attr) {
        hipFuncSetAttribute(reinterpret_cast<const void*>(&gemm8p<0>),
                            hipFuncAttributeMaxDynamicSharedMemorySize, 131072);
        hipFuncSetAttribute(reinterpret_cast<const void*>(&gemm8p<1>),
                            hipFuncAttributeMaxDynamicSharedMemorySize, 131072);
        s_attr = true;
    }

    const int nTrTiles = (T >> 6) * (Dout >> 6);
    const int nRowBlocks = 1024;  // 4096 waves grid-striding M+T rows
    prep_kernel<<<nRowBlocks + nTrTiles, 256, 0, stream>>>(
        x, key, temp, val, xb, kf, VT, rowsq, M, T, D, Dout, nRowBlocks);
    gemm8p<0><<<dim3(M / 256, T / 256), 512, 131072, stream>>>(xb, kf, sim,
                                                               rowsq, M, T, D);
    int t8shift = 0;
    {
        int t8 = T >> 3;
        while ((1 << t8shift) < t8) t8shift++;
    }
    gelu_kernel<<<2048, 256, 0, stream>>>(sim, rowsq, M * (T >> 3), t8shift,
                                          sqrtf((float)T));
    gemm8p<1><<<dim3(M / 256, Dout / 256), 512, 131072, stream>>>(
        sim, VT, out, nullptr, M, Dout, T);
}